// Round 1
// baseline (497.616 us; speedup 1.0000x reference)
//
#include <hip/hip_runtime.h>
#include <cmath>

#define NUM_S   64
#define IMG_H   256
#define IMG_W   256
#define HWSZ    (IMG_H*IMG_W)          // 65536
#define BATCH   2
#define NPIX    (BATCH*HWSZ)           // 131072
#define NEL     (BATCH*NUM_S*HWSZ)     // 8388608
#define NSLICE  (BATCH*NUM_S)          // 128
#define VALID   246
#define INV_T   2.0f                   // 1/TEMP, TEMP=0.5
#define EPS_F   1e-20f
#define C1_F    1e-4f
#define C2_F    9e-4f

struct GK { float g[11]; };

// block-wide sum of a float, one double atomicAdd per block
__device__ inline void block_atomic_add(float v, double* dst) {
    __shared__ float sm[8];
    __syncthreads();                       // protect sm across repeated calls
    #pragma unroll
    for (int off = 32; off; off >>= 1) v += __shfl_down(v, off, 64);
    int lane = threadIdx.x & 63, w = threadIdx.x >> 6;
    if (lane == 0) sm[w] = v;
    __syncthreads();
    if (threadIdx.x == 0) {
        double s = 0.0;
        int nw = blockDim.x >> 6;
        for (int i = 0; i < nw; ++i) s += (double)sm[i];
        atomicAdd(dst, s);
    }
}

// Kernel 1: per-pixel online-softmax scan over slices (fwd + bwd as separate
// thread halves), writes p1/t1/p2/t2 and fuses the three L1 sums.
// acc[0]=sum|img-tgt|, acc[1]=sum|p1-t1|, acc[2]=sum|p2-t2|
__global__ __launch_bounds__(256) void scan_kernel(
    const float* __restrict__ img, const float* __restrict__ tgt,
    const float* __restrict__ un,
    float* __restrict__ p1, float* __restrict__ t1,
    float* __restrict__ p2, float* __restrict__ t2,
    double* __restrict__ acc)
{
    int tid = blockIdx.x * 256 + threadIdx.x;
    bool bwd = tid >= NPIX;                 // whole block is one direction
    int pix = bwd ? tid - NPIX : tid;
    int b  = pix >> 16;                     // pix / HWSZ
    int hw = pix & (HWSZ - 1);
    int base = b * (NUM_S * HWSZ) + hw;

    float m = -INFINITY, num = 0.f, den = 0.f, tmax = -INFINITY;
    float l1x = 0.f, l1p = 0.f;
    for (int i = 0; i < NUM_S; ++i) {
        int s = bwd ? (NUM_S - 1 - i) : i;
        int idx = base + s * HWSZ;
        float x = img[idx];
        float u = un[idx];
        float t = tgt[idx];
        float gmb = -__logf(-__logf(u + EPS_F) + EPS_F);
        float yv = x + gmb;
        // online softmax update (equivalent to global-max-subtract cumsum)
        float mn = fmaxf(m, yv);
        float sc = __expf((m - mn) * INV_T);   // m=-inf first iter -> 0
        float e  = __expf((yv - mn) * INV_T);
        num = num * sc + e * x;
        den = den * sc + e;
        m = mn;
        float p = num / den;
        tmax = fmaxf(tmax, t);
        if (!bwd) {
            p1[idx] = p; t1[idx] = tmax;
            l1x += fabsf(x - t);
        } else {
            // slice order is irrelevant for L1/SSIM -> write at natural index
            p2[idx] = p; t2[idx] = tmax;
        }
        l1p += fabsf(p - tmax);
    }
    block_atomic_add(l1x, &acc[0]);              // bwd blocks add 0
    block_atomic_add(l1p, bwd ? &acc[2] : &acc[1]);
}

// Kernel 2: fused separable-Gaussian SSIM sum for one pair (blockIdx.z).
// Block = 32x32 output tile of one slice. Vertical blur: direct-from-global
// (L2-resident slice) with 8-row register blocking -> 5 fields into LDS.
// Horizontal blur + SSIM from LDS with aligned b128 reads.
// acc[3+pair] accumulates sum of ssim_map.
__global__ __launch_bounds__(128) void ssim_kernel(
    const float* __restrict__ xa, const float* __restrict__ ya,
    const float* __restrict__ xb, const float* __restrict__ yb,
    const float* __restrict__ xc, const float* __restrict__ yc,
    GK gk, double* __restrict__ acc)
{
    __shared__ float v[5][32 * 44];       // stride 44 keeps 16B alignment
    int pair = blockIdx.z;
    const float* __restrict__ xp = pair == 0 ? xa : (pair == 1 ? xb : xc);
    const float* __restrict__ yp = pair == 0 ? ya : (pair == 1 ? yb : yc);
    int base = blockIdx.y * HWSZ;         // slice base
    int ty = blockIdx.x >> 3, tx = blockIdx.x & 7;
    int r0 = ty * 32, c0 = tx * 32;       // output-tile origin
    int rmax = min(32, VALID - r0);
    int cmax = min(32, VALID - c0);

    // ---- vertical blur: 42 cols x 4 row-groups(8 rows) = 168 tasks ----
    for (int task = threadIdx.x; task < 168; task += 128) {
        int c  = task % 42;
        int rg = task / 42;
        int rb = rg * 8;
        int gc = min(c0 + c, IMG_W - 1);  // clamp only touches unused outputs
        float ax[18], ay[18];
        #pragma unroll
        for (int k = 0; k < 18; ++k) {
            int gr = min(r0 + rb + k, IMG_H - 1);
            int idx = base + gr * IMG_W + gc;
            ax[k] = xp[idx];
            ay[k] = yp[idx];
        }
        #pragma unroll
        for (int j = 0; j < 8; ++j) {
            float sx = 0, sy = 0, sxx = 0, syy = 0, sxy = 0;
            #pragma unroll
            for (int k = 0; k < 11; ++k) {
                float w  = gk.g[k];
                float xv = ax[j + k], yv = ay[j + k];
                sx  += w * xv;      sy  += w * yv;
                sxx += w * xv * xv; syy += w * yv * yv;
                sxy += w * xv * yv;
            }
            int row = rb + j;
            v[0][row * 44 + c] = sx;
            v[1][row * 44 + c] = sy;
            v[2][row * 44 + c] = sxx;
            v[3][row * 44 + c] = syy;
            v[4][row * 44 + c] = sxy;
        }
    }
    __syncthreads();

    // ---- horizontal blur + SSIM: 32 rows x 4 col-groups(8 cols) = 128 ----
    float lsum = 0.f;
    {
        int r  = threadIdx.x >> 2;
        int cb = (threadIdx.x & 3) * 8;
        if (r < rmax) {
            float o[5][8];
            #pragma unroll
            for (int f = 0; f < 5; ++f) {
                float t[20];
                #pragma unroll
                for (int k = 0; k < 20; ++k) t[k] = v[f][r * 44 + cb + k];
                #pragma unroll
                for (int j = 0; j < 8; ++j) {
                    float a = 0;
                    #pragma unroll
                    for (int k = 0; k < 11; ++k) a += gk.g[k] * t[j + k];
                    o[f][j] = a;
                }
            }
            #pragma unroll
            for (int j = 0; j < 8; ++j) {
                if (cb + j < cmax) {
                    float m1 = o[0][j], m2 = o[1][j];
                    float s11 = o[2][j] - m1 * m1;
                    float s22 = o[3][j] - m2 * m2;
                    float s12 = o[4][j] - m1 * m2;
                    float nv = (2.f * m1 * m2 + C1_F) * (2.f * s12 + C2_F);
                    float dv = (m1 * m1 + m2 * m2 + C1_F) * (s11 + s22 + C2_F);
                    lsum += nv / dv;
                }
            }
        }
    }
    block_atomic_add(lsum, &acc[3 + pair]);
}

__global__ void finalize_kernel(const double* __restrict__ acc,
                                float* __restrict__ out) {
    double l1 = (acc[0] + acc[1] + acc[2]) / (double)NEL;
    double ss = (acc[3] + acc[4] + acc[5]) /
                ((double)NSLICE * (double)VALID * (double)VALID);
    out[0] = (float)(3.0 + l1 - ss);
}

extern "C" void kernel_launch(void* const* d_in, const int* in_sizes, int n_in,
                              void* d_out, int out_size, void* d_ws, size_t ws_size,
                              hipStream_t stream) {
    const float* img = (const float*)d_in[0];
    const float* tgt = (const float*)d_in[1];
    const float* un  = (const float*)d_in[2];
    float* out = (float*)d_out;

    // workspace: p1,t1,p2,t2 (32MB each) + 6 double accumulators
    float* p1 = (float*)d_ws;
    float* t1 = p1 + NEL;
    float* p2 = t1 + NEL;
    float* t2 = p2 + NEL;
    double* acc = (double*)(t2 + NEL);

    hipMemsetAsync(acc, 0, 6 * sizeof(double), stream);

    GK gk;  // gaussian(11, sigma=1.5) computed in double, matches reference
    {
        double c[11], s = 0.0;
        for (int i = 0; i < 11; ++i) { double d = i - 5; c[i] = exp(-d * d / 4.5); s += c[i]; }
        for (int i = 0; i < 11; ++i) gk.g[i] = (float)(c[i] / s);
    }

    scan_kernel<<<(2 * NPIX) / 256, 256, 0, stream>>>(img, tgt, un, p1, t1, p2, t2, acc);
    ssim_kernel<<<dim3(64, NSLICE, 3), 128, 0, stream>>>(img, tgt, p1, t1, p2, t2, gk, acc);
    finalize_kernel<<<1, 1, 0, stream>>>(acc, out);
}